// Round 5
// baseline (693.746 us; speedup 1.0000x reference)
//
#include <hip/hip_runtime.h>

// LGCN_Encoder — Gram collapse + fragment-blocked global layouts.
//   G = V^T V (512x512), c0 = V^T ego0, c_{k+1} = G(f_k ⊙ c_k),
//   out = (ego0 + V(f0⊙c0 + f1⊙c1 + f2⊙c2)) / 4.
// VTF[T][O][lane][8]: V in MFMA fragment order (T=f/16, O=n/32,
// lane=(m16=f%16)+16*(quad=n-oct), 8 consecutive n per lane). A-frags and
// B-frags of 16x16x32 share this layout -> gram is LDS-free with every load
// a 64-lane-contiguous dwordx4 (fixes R2/R3's 16-line divergent gathers).
// MFMA 16x16x32_bf16 (HW-verified m89/m91): A[m=lane&15][k=quad*8+j],
// B[k=quad*8+j][col=lane&15], C[row=quad*4+reg][col=lane&15].

#define N_USERS 29858
#define N_TOTAL 70839
#define DQ 64
#define FD 512
#define NPAD 71168          // 556*128
#define OPC 2224            // NPAD/32 n-octs
#define NC_G 32             // gram split-K chunks
#define OLEN 70             // ceil(OPC/NC_G)

typedef __attribute__((ext_vector_type(8))) short short8;
typedef __attribute__((ext_vector_type(4))) float f32x4;
typedef unsigned int u32;
typedef unsigned short u16;

static __device__ __forceinline__ u32 f32u(float x){union{float f;u32 u;}a;a.f=x;return a.u;}
static __device__ __forceinline__ float uf32(u32 u){union{u32 u;float f;}a;a.u=u;return a.f;}
static __device__ __forceinline__ u32 pack_h(u32 x0, u32 x1){
  return __builtin_amdgcn_perm(x1, x0, 0x07060302u);  // (hi16(x1)<<16)|hi16(x0)
}
// exact trunc split of two f32 into packed bf16 hi-pair / lo-pair
static __device__ __forceinline__ void split_pair(u32 x0, u32 x1, u32& hp, u32& lp) {
  hp = pack_h(x0, x1);
  u32 l0 = f32u(uf32(x0) - uf32(x0 & 0xFFFF0000u));
  u32 l1 = f32u(uf32(x1) - uf32(x1 & 0xFFFF0000u));
  lp = pack_h(l0, l1);
}
union U8x { u32 u[4]; short8 s; };

// ---------------------------------------------------------------- build_vtf
// VTF_h/l fragment-blocked transpose of V. Block: 64 f x 128 n.
__global__ __launch_bounds__(256) void build_vtf(
    const float* __restrict__ v, u16* __restrict__ vth, u16* __restrict__ vtl) {
  __shared__ float SR[128 * 68];  // [n_loc][f_loc], pitch 68 (16B-aligned rows)
  const int fb = blockIdx.x * 64;
  const int nb = blockIdx.y * 128;
  const int t = threadIdx.x;
#pragma unroll
  for (int rd = 0; rd < 8; ++rd) {
    int flat = rd * 256 + t;
    int row = flat >> 4, c4 = flat & 15;
    int n = nb + row;
    f32x4 val = {0.f, 0.f, 0.f, 0.f};
    if (n < N_TOTAL) val = *(const f32x4*)(v + (size_t)n * FD + fb + c4 * 4);
    *(f32x4*)(&SR[row * 68 + c4 * 4]) = val;
  }
  __syncthreads();
  const int lane = t & 63, wv = t >> 6;
  const int m16 = lane & 15, quad = lane >> 4;
#pragma unroll
  for (int rd = 0; rd < 4; ++rd) {
    int slot = rd * 4 + wv;            // 16 slots = 4 T_loc x 4 O_loc
    int T_loc = slot & 3, O_loc = slot >> 2;
    int f_loc = T_loc * 16 + m16;
    int n0 = O_loc * 32 + quad * 8;
    u32 xu[8];
#pragma unroll
    for (int j = 0; j < 8; ++j) xu[j] = f32u(SR[(n0 + j) * 68 + f_loc]);
    U8x H, L;
#pragma unroll
    for (int p = 0; p < 4; ++p) split_pair(xu[2 * p], xu[2 * p + 1], H.u[p], L.u[p]);
    size_t Tg = (size_t)blockIdx.x * 4 + T_loc;
    size_t Og = (size_t)blockIdx.y * 4 + O_loc;
    size_t sa = ((Tg * OPC + Og) * 64 + lane) * 8;
    *(short8*)(vth + sa) = H.s;
    *(short8*)(vtl + sa) = L.s;
  }
}

// ---------------------------------------------------------------- init_ego
// out = concat(user,item); egoTF fragment-blocked (4 Td x OPC). Block: 128 n.
__global__ __launch_bounds__(256) void init_ego(
    const float* __restrict__ ue, const float* __restrict__ ie,
    float* __restrict__ out, u16* __restrict__ egh, u16* __restrict__ egl) {
  __shared__ float SR[128 * 68];
  const int nb = blockIdx.x * 128;
  const int t = threadIdx.x;
#pragma unroll
  for (int rd = 0; rd < 8; ++rd) {
    int flat = rd * 256 + t;
    int row = flat >> 4, c4 = flat & 15;
    int n = nb + row;
    f32x4 val = {0.f, 0.f, 0.f, 0.f};
    if (n < N_TOTAL) {
      const float* src = (n < N_USERS) ? ue + (size_t)n * DQ
                                       : ie + (size_t)(n - N_USERS) * DQ;
      val = *(const f32x4*)(src + c4 * 4);
      *(f32x4*)(out + (size_t)n * DQ + c4 * 4) = val;
    }
    *(f32x4*)(&SR[row * 68 + c4 * 4]) = val;
  }
  __syncthreads();
  const int lane = t & 63, wv = t >> 6;
  const int m16 = lane & 15, quad = lane >> 4;
#pragma unroll
  for (int rd = 0; rd < 4; ++rd) {
    int slot = rd * 4 + wv;
    int T_loc = slot & 3, O_loc = slot >> 2;
    int d_loc = T_loc * 16 + m16;
    int n0 = O_loc * 32 + quad * 8;
    u32 xu[8];
#pragma unroll
    for (int j = 0; j < 8; ++j) xu[j] = f32u(SR[(n0 + j) * 68 + d_loc]);
    U8x H, L;
#pragma unroll
    for (int p = 0; p < 4; ++p) split_pair(xu[2 * p], xu[2 * p + 1], H.u[p], L.u[p]);
    size_t Og = (size_t)blockIdx.x * 4 + O_loc;
    size_t sa = (((size_t)T_loc * OPC + Og) * 64 + lane) * 8;
    *(short8*)(egh + sa) = H.s;
    *(short8*)(egl + sa) = L.s;
  }
}

// ---------------------------------------------------------------- gram core
template <int NCT>
static __device__ __forceinline__ void gram_core(
    const u16* __restrict__ Ah, const u16* __restrict__ Al,
    const u16* __restrict__ Bh, const u16* __restrict__ Bl,
    size_t off, int steps, f32x4 (&acc)[2][NCT]) {
  const size_t TS = (size_t)OPC * 512;
  for (int s = 0; s < steps; ++s) {
    short8 a_h[2], a_l[2];
#pragma unroll
    for (int mt = 0; mt < 2; ++mt) {
      a_h[mt] = *(const short8*)(Ah + mt * TS + off);
      a_l[mt] = *(const short8*)(Al + mt * TS + off);
    }
#pragma unroll
    for (int ct = 0; ct < NCT; ++ct) {
      short8 b_h = *(const short8*)(Bh + ct * TS + off);
      short8 b_l = *(const short8*)(Bl + ct * TS + off);
#pragma unroll
      for (int mt = 0; mt < 2; ++mt) {
        acc[mt][ct] = __builtin_amdgcn_mfma_f32_16x16x32_bf16(a_h[mt], b_h, acc[mt][ct], 0, 0, 0);
        acc[mt][ct] = __builtin_amdgcn_mfma_f32_16x16x32_bf16(a_h[mt], b_l, acc[mt][ct], 0, 0, 0);
        acc[mt][ct] = __builtin_amdgcn_mfma_f32_16x16x32_bf16(a_l[mt], b_h, acc[mt][ct], 0, 0, 0);
      }
    }
    off += 512;
  }
}

// ---------------------------------------------------------------- gram
// jobs 0..9: upper-tri 128x128 G tiles; 10..13: c0 tiles (128f x 64d).
// LDS-free; all loads 64-lane-contiguous 1KB. Split-K atomics into G/c0.
__global__ __launch_bounds__(256, 2) void gram_kernel(
    const u16* __restrict__ vth, const u16* __restrict__ vtl,
    const u16* __restrict__ egh, const u16* __restrict__ egl,
    float* __restrict__ G, float* __restrict__ c0) {
  const int job = blockIdx.x;
  const int t = threadIdx.x, lane = t & 63, wv = t >> 6;
  const int m16 = lane & 15, quad = lane >> 4;
  const int Os = blockIdx.y * OLEN;
  const int Oe = min(Os + OLEN, OPC);
  const int steps = Oe - Os;
  const size_t TS = (size_t)OPC * 512;
  size_t off0 = (size_t)Os * 512 + (size_t)lane * 8;

  int ti, tj;
  if (job < 4)       { ti = 0; tj = job; }
  else if (job < 7)  { ti = 1; tj = job - 3; }
  else if (job < 9)  { ti = 2; tj = job - 5; }
  else if (job < 10) { ti = 3; tj = 3; }
  else               { ti = job - 10; tj = -1; }

  const u16* Ah = vth + (size_t)(ti * 8 + wv * 2) * TS;
  const u16* Al = vtl + (size_t)(ti * 8 + wv * 2) * TS;

  if (tj < 0) {
    f32x4 acc[2][4];
#pragma unroll
    for (int a = 0; a < 2; ++a)
#pragma unroll
      for (int b = 0; b < 4; ++b) acc[a][b] = (f32x4){0.f, 0.f, 0.f, 0.f};
    gram_core<4>(Ah, Al, egh, egl, off0, steps, acc);
#pragma unroll
    for (int mt = 0; mt < 2; ++mt) {
      int row = ti * 128 + wv * 32 + mt * 16 + quad * 4;
#pragma unroll
      for (int ct = 0; ct < 4; ++ct)
#pragma unroll
        for (int reg = 0; reg < 4; ++reg)
          atomicAdd(&c0[(row + reg) * DQ + ct * 16 + m16], acc[mt][ct][reg]);
    }
  } else {
    f32x4 acc[2][8];
#pragma unroll
    for (int a = 0; a < 2; ++a)
#pragma unroll
      for (int b = 0; b < 8; ++b) acc[a][b] = (f32x4){0.f, 0.f, 0.f, 0.f};
    gram_core<8>(Ah, Al, vth + (size_t)(tj * 8) * TS, vtl + (size_t)(tj * 8) * TS,
                 off0, steps, acc);
#pragma unroll
    for (int mt = 0; mt < 2; ++mt) {
      int row = ti * 128 + wv * 32 + mt * 16 + quad * 4;
#pragma unroll
      for (int ct = 0; ct < 8; ++ct)
#pragma unroll
        for (int reg = 0; reg < 4; ++reg)
          atomicAdd(&G[(row + reg) * FD + tj * 128 + ct * 16 + m16], acc[mt][ct][reg]);
    }
  }
}

// ---------------------------------------------------------------- mirror
__global__ __launch_bounds__(256) void mirror_kernel(float* __restrict__ G) {
  int idx = blockIdx.x * 256 + threadIdx.x;
  int r = idx >> 9, c = idx & 511;
  if (c < r) G[idx] = G[c * 512 + r];
}

// ---------------------------------------------------------------- apply_g
// cout = G @ (filt ⊙ cin). One block per G-row, 4-way K-split + LDS reduce.
__global__ __launch_bounds__(256) void apply_g(
    const float* __restrict__ G, const float* __restrict__ filt,
    const float* __restrict__ cin, float* __restrict__ cout) {
  __shared__ float red[4][64];
  const int i = blockIdx.x;
  const int d = threadIdx.x & 63, kq = threadIdx.x >> 6;
  float s = 0.f;
#pragma unroll 8
  for (int j = kq * 128; j < kq * 128 + 128; ++j)
    s += G[i * 512 + j] * filt[j] * cin[j * 64 + d];
  red[kq][d] = s;
  __syncthreads();
  if (kq == 0) cout[i * 64 + d] = red[0][d] + red[1][d] + red[2][d] + red[3][d];
}

// ---------------------------------------------------------------- prep_wtf
// wsum = f0⊙c0 + f1⊙c1 + f2⊙c2, emitted fragment-blocked for expand's B.
__global__ __launch_bounds__(256) void prep_wtf(
    const float* __restrict__ filters, const float* __restrict__ c0,
    const float* __restrict__ c1, const float* __restrict__ c2,
    u16* __restrict__ wth, u16* __restrict__ wtl) {
  int idx = blockIdx.x * 256 + threadIdx.x;   // 4096 = 4 ct x 16 Of x 64 lanes
  int lane = idx & 63;
  int Of = (idx >> 6) & 15;
  int ct = idx >> 10;
  int d = ct * 16 + (lane & 15);
  int f0 = Of * 32 + (lane >> 4) * 8;
  u32 xu[8];
#pragma unroll
  for (int j = 0; j < 8; ++j) {
    int f = f0 + j;
    float w = filters[f] * c0[f * 64 + d] + filters[512 + f] * c1[f * 64 + d]
            + filters[1024 + f] * c2[f * 64 + d];
    xu[j] = f32u(w);
  }
  U8x H, L;
#pragma unroll
  for (int p = 0; p < 4; ++p) split_pair(xu[2 * p], xu[2 * p + 1], H.u[p], L.u[p]);
  *(short8*)(wth + (size_t)idx * 8) = H.s;
  *(short8*)(wtl + (size_t)idx * 8) = L.s;
}

// ---------------------------------------------------------------- expand
// out = (out + V @ wsum) * 0.25. A: raw fp32 rows staged in LDS (pitch 68,
// conflict-free b128 frag reads), split in-reg. B: wtF contiguous dwordx4.
__global__ __launch_bounds__(256) void expand_kernel(
    const float* __restrict__ v, const u16* __restrict__ wth,
    const u16* __restrict__ wtl, float* __restrict__ out) {
  __shared__ float SR[128 * 68];
  const int t = threadIdx.x, lane = t & 63, wv = t >> 6;
  const int m16 = lane & 15, quad = lane >> 4;
  const int nb = blockIdx.x * 128;

  f32x4 acc[2][4];
#pragma unroll
  for (int a = 0; a < 2; ++a)
#pragma unroll
    for (int b = 0; b < 4; ++b) acc[a][b] = (f32x4){0.f, 0.f, 0.f, 0.f};

  for (int fs = 0; fs < FD; fs += 64) {
    __syncthreads();
#pragma unroll
    for (int rd = 0; rd < 8; ++rd) {
      int flat = rd * 256 + t;
      int row = flat >> 4, c4 = flat & 15;
      int n = nb + row;
      f32x4 val = {0.f, 0.f, 0.f, 0.f};
      if (n < N_TOTAL) val = *(const f32x4*)(v + (size_t)n * FD + fs + c4 * 4);
      *(f32x4*)(&SR[row * 68 + c4 * 4]) = val;
    }
    __syncthreads();
#pragma unroll
    for (int k0 = 0; k0 < 64; k0 += 32) {
      short8 a_h[2], a_l[2];
#pragma unroll
      for (int mt = 0; mt < 2; ++mt) {
        const float* rp = SR + (wv * 32 + mt * 16 + m16) * 68 + k0 + quad * 8;
        f32x4 xa = *(const f32x4*)rp;
        f32x4 xb = *(const f32x4*)(rp + 4);
        U8x H, L;
        split_pair(f32u(xa[0]), f32u(xa[1]), H.u[0], L.u[0]);
        split_pair(f32u(xa[2]), f32u(xa[3]), H.u[1], L.u[1]);
        split_pair(f32u(xb[0]), f32u(xb[1]), H.u[2], L.u[2]);
        split_pair(f32u(xb[2]), f32u(xb[3]), H.u[3], L.u[3]);
        a_h[mt] = H.s; a_l[mt] = L.s;
      }
      int Of = (fs + k0) >> 5;
#pragma unroll
      for (int ct = 0; ct < 4; ++ct) {
        size_t boff = ((size_t)(ct * 16 + Of) * 64 + lane) * 8;
        short8 b_h = *(const short8*)(wth + boff);
        short8 b_l = *(const short8*)(wtl + boff);
#pragma unroll
        for (int mt = 0; mt < 2; ++mt) {
          acc[mt][ct] = __builtin_amdgcn_mfma_f32_16x16x32_bf16(a_h[mt], b_h, acc[mt][ct], 0, 0, 0);
          acc[mt][ct] = __builtin_amdgcn_mfma_f32_16x16x32_bf16(a_h[mt], b_l, acc[mt][ct], 0, 0, 0);
          acc[mt][ct] = __builtin_amdgcn_mfma_f32_16x16x32_bf16(a_l[mt], b_h, acc[mt][ct], 0, 0, 0);
        }
      }
    }
  }

#pragma unroll
  for (int mt = 0; mt < 2; ++mt) {
    int nrow = nb + wv * 32 + mt * 16 + quad * 4;
#pragma unroll
    for (int ct = 0; ct < 4; ++ct) {
      int d = ct * 16 + m16;
#pragma unroll
      for (int reg = 0; reg < 4; ++reg) {
        int n = nrow + reg;
        if (n < N_TOTAL) {
          float* op = out + (size_t)n * DQ + d;
          *op = (*op + acc[mt][ct][reg]) * 0.25f;
        }
      }
    }
  }
}

// ---------------------------------------------------------------- launch
extern "C" void kernel_launch(void* const* d_in, const int* in_sizes, int n_in,
                              void* d_out, int out_size, void* d_ws, size_t ws_size,
                              hipStream_t stream) {
  const float* user_emb = (const float*)d_in[0];
  const float* item_emb = (const float*)d_in[1];
  const float* v        = (const float*)d_in[2];
  const float* filters  = (const float*)d_in[3];
  float* out = (float*)d_out;

  const size_t TS = (size_t)OPC * 512;       // u16 per 16-f fragment stream
  u16* vth  = (u16*)d_ws;                    // 32*TS  (72.9 MB)
  u16* vtl  = vth + 32 * TS;                 // 32*TS
  u16* egh  = vtl + 32 * TS;                 // 4*TS   (9.1 MB)
  u16* egl  = egh + 4 * TS;                  // 4*TS
  float* G  = (float*)(egl + 4 * TS);        // 512*512
  float* c0 = G + 512 * 512;                 // 512*64
  float* c1 = c0 + 512 * 64;
  float* c2 = c1 + 512 * 64;
  u16* wth  = (u16*)(c2 + 512 * 64);         // 4096*8
  u16* wtl  = wth + 4096 * 8;

  build_vtf<<<dim3(8, NPAD / 128), 256, 0, stream>>>(v, vth, vtl);
  init_ego<<<NPAD / 128, 256, 0, stream>>>(user_emb, item_emb, out, egh, egl);
  hipMemsetAsync(G, 0, (size_t)(512 * 512 + 512 * 64) * sizeof(float), stream);
  gram_kernel<<<dim3(14, NC_G), 256, 0, stream>>>(vth, vtl, egh, egl, G, c0);
  mirror_kernel<<<(512 * 512) / 256, 256, 0, stream>>>(G);
  apply_g<<<512, 256, 0, stream>>>(G, filters, c0, c1);
  apply_g<<<512, 256, 0, stream>>>(G, filters + 512, c1, c2);
  prep_wtf<<<16, 256, 0, stream>>>(filters, c0, c1, c2, wth, wtl);
  expand_kernel<<<NPAD / 128, 256, 0, stream>>>(v, wth, wtl, out);
}